// Round 5
// baseline (5991.533 us; speedup 1.0000x reference)
//
#include <hip/hip_runtime.h>
#include <hip/hip_bf16.h>
#include <math.h>

#define AA 32
#define BB 2048
#define BP1 2049
#define CC 256
#define NROWS (AA * BP1)          // 65568
#define NHEAD 8
#define DHEAD 32
#define NBLK 3
#define FFN 1024

using bf16 = __hip_bfloat16;
typedef unsigned int uint;
typedef unsigned short ushort_t;
typedef __attribute__((ext_vector_type(4))) float f32x4;
typedef __attribute__((ext_vector_type(8))) short short8;

// epilogue flag bits for mm_k (wave-uniform runtime flags)
#define F_RSAE   1
#define F_ROWMAP 2
#define F_BIAS2D 4
#define F_BIAS1D 8
#define F_GELU   16
#define F_RESID  32
#define F_OUTB16 64

__device__ __forceinline__ float bf2f(unsigned short u) {
    return __uint_as_float(((unsigned int)u) << 16);
}
__device__ __forceinline__ unsigned short f2b(float x) {   // fp32 -> bf16 RNE
    uint u = __float_as_uint(x);
    u += 0x7fff + ((u >> 16) & 1);
    return (unsigned short)(u >> 16);
}
__device__ __forceinline__ uint packsplit(float x) {       // {hi16, lo16}
    unsigned short h = f2b(x);
    unsigned short l = f2b(x - bf2f(h));
    return (((uint)h) << 16) | (uint)l;
}

// ---------------- fp32 -> packed split ----------------
__global__ __launch_bounds__(256) void pack_k(const float* __restrict__ src,
                                              uint* __restrict__ dst, int n) {
    int i = blockIdx.x * 256 + threadIdx.x;
    if (i < n) dst[i] = packsplit(src[i]);
}

// ---------------- row 0 of each batch: cls + bias (round-1 verbatim) ----------------
__global__ __launch_bounds__(256) void row0_k(float* __restrict__ out,
                                              const float* __restrict__ cls,
                                              const float* __restrict__ bias) {
    int i = blockIdx.x, t = threadIdx.x;
    size_t o = (size_t)i * BP1 * CC + t;
    out[o] = cls[i * CC + t] + bias[o];
}

// ---------------- layernorm f32 (round-1 verbatim) ----------------
__global__ __launch_bounds__(256) void ln_k(const float* __restrict__ in, float* __restrict__ out,
                                            const float* __restrict__ g, const float* __restrict__ b) {
    int row = blockIdx.x * 4 + (threadIdx.x >> 6);
    int lane = threadIdx.x & 63;
    const float4 v = *reinterpret_cast<const float4*>(in + (size_t)row * CC + lane * 4);
    float s = v.x + v.y + v.z + v.w;
    float sq = v.x * v.x + v.y * v.y + v.z * v.z + v.w * v.w;
    #pragma unroll
    for (int m = 1; m < 64; m <<= 1) { s += __shfl_xor(s, m); sq += __shfl_xor(sq, m); }
    float mu = s * (1.0f / CC);
    float var = sq * (1.0f / CC) - mu * mu;
    float rs = rsqrtf(var + 1e-5f);
    const float4 gg = *reinterpret_cast<const float4*>(g + lane * 4);
    const float4 bb = *reinterpret_cast<const float4*>(b + lane * 4);
    float4 o;
    o.x = (v.x - mu) * rs * gg.x + bb.x;
    o.y = (v.y - mu) * rs * gg.y + bb.y;
    o.z = (v.z - mu) * rs * gg.z + bb.z;
    o.w = (v.w - mu) * rs * gg.w + bb.w;
    *reinterpret_cast<float4*>(out + (size_t)row * CC + lane * 4) = o;
}

// ---------------- Wqkv pre-transpose (round-1 verbatim) ----------------
__global__ __launch_bounds__(256) void wqkv_t_k(const float* __restrict__ Wqkv, float* __restrict__ wt) {
    int idx = blockIdx.x * 256 + threadIdx.x;        // 589824 total
    int c = idx % 96;
    int k = (idx / 96) & 255;
    int h = (idx / (96 * 256)) & 7;
    int a = idx / (96 * 256 * 8);
    int x = c >> 5, d = c & 31;
    wt[idx] = Wqkv[((((size_t)a * 3 + x) * NHEAD + h) * DHEAD + d) * CC + k];
}

// ---------------- fused qkv gemm + rsa + imv (round-1 verbatim) ----------------
__global__ __launch_bounds__(256) void qkv_k(const float* __restrict__ z,
                                             const float* __restrict__ wt,
                                             float* __restrict__ imv) {
    __shared__ float zs[32][257];
    __shared__ float wsh[64][100];
    __shared__ float qs[32][100];
    const int t = threadIdx.x;
    const int r0 = blockIdx.x * 32;

    #pragma unroll
    for (int rr = 0; rr < 32; ++rr)
        zs[rr][t] = z[(size_t)(r0 + rr) * CC + t];

    const int r = t >> 3;            // 0..31
    const int c0 = (t & 7) * 12;     // 0,12,..,84

    for (int h = 0; h < NHEAD; ++h) {
        float acc[12] = {};
        for (int kb = 0; kb < 4; ++kb) {
            __syncthreads();
            #pragma unroll
            for (int n = 0; n < 24; ++n) {          // 96*64/256
                int idx = n * 256 + t;
                int kk = idx / 96;
                int cc2 = idx - kk * 96;
                wsh[kk][cc2] = wt[((size_t)h * 256 + kb * 64 + kk) * 96 + cc2];
            }
            __syncthreads();
            #pragma unroll
            for (int kk = 0; kk < 64; ++kk) {
                float zv = zs[r][kb * 64 + kk];
                float4 w0 = *reinterpret_cast<const float4*>(&wsh[kk][c0]);
                float4 w1 = *reinterpret_cast<const float4*>(&wsh[kk][c0 + 4]);
                float4 w2 = *reinterpret_cast<const float4*>(&wsh[kk][c0 + 8]);
                acc[0] += zv * w0.x; acc[1]  += zv * w0.y; acc[2]  += zv * w0.z; acc[3]  += zv * w0.w;
                acc[4] += zv * w1.x; acc[5]  += zv * w1.y; acc[6]  += zv * w1.z; acc[7]  += zv * w1.w;
                acc[8] += zv * w2.x; acc[9]  += zv * w2.y; acc[10] += zv * w2.z; acc[11] += zv * w2.w;
            }
        }
        __syncthreads();
        #pragma unroll
        for (int j = 0; j < 12; ++j) qs[r][c0 + j] = acc[j];
        __syncthreads();
        {
            int d0 = (t & 7) * 4;
            float p = 0.f;
            #pragma unroll
            for (int e = 0; e < 4; ++e) p += qs[r][d0 + e] * qs[r][32 + d0 + e];
            p += __shfl_xor(p, 1); p += __shfl_xor(p, 2); p += __shfl_xor(p, 4);
            float sc = p * 0.17677669529663689f;     // 1/sqrt(32)
            float4 o = make_float4(sc * qs[r][64 + d0], sc * qs[r][64 + d0 + 1],
                                   sc * qs[r][64 + d0 + 2], sc * qs[r][64 + d0 + 3]);
            *reinterpret_cast<float4*>(imv + (size_t)(r0 + r) * CC + h * DHEAD + d0) = o;
        }
    }
}

// ---------------- cumsum (round-1 verbatim, f32) ----------------
__global__ __launch_bounds__(256) void cumsum1_k(float* __restrict__ imv, float* __restrict__ tot) {
    int i = blockIdx.x >> 3, ch = blockIdx.x & 7, c = threadIdx.x;
    size_t base = ((size_t)i * BP1 + ch * 256) * CC + c;
    float acc = 0.f;
    for (int j = 0; j < 256; ++j) {
        acc += imv[base + (size_t)j * CC];
        imv[base + (size_t)j * CC] = acc;
    }
    tot[((size_t)i * 8 + ch) * CC + c] = acc;
}

__global__ __launch_bounds__(256) void cumsum2_k(float* __restrict__ imv, const float* __restrict__ tot) {
    int i = blockIdx.x >> 3, ch = blockIdx.x & 7, c = threadIdx.x;
    if (ch == 0) return;
    float off = 0.f;
    for (int p = 0; p < ch; ++p) off += tot[((size_t)i * 8 + p) * CC + c];
    size_t base = ((size_t)i * BP1 + ch * 256) * CC + c;
    for (int j = 0; j < 256; ++j) imv[base + (size_t)j * CC] += off;
}

// ---------------- tiled fp32 gemm (round-1 verbatim) ----------------
template<bool ABF16, bool OBF16, bool ROWMAP, bool BIAS2D, bool BIAS1D, bool RESID, bool GELU>
__global__ __launch_bounds__(256) void gemm_k(const void* __restrict__ Ap,
                                              const float* __restrict__ W,
                                              void* __restrict__ Op,
                                              const float* __restrict__ bias,
                                              int M, int K, int NC) {
    __shared__ float as[16][68];
    __shared__ float bs[16][68];
    const int t = threadIdx.x;
    const int m0 = blockIdx.x * 64;
    const int n0 = blockIdx.y * 64;
    const int ty = t >> 4, tx = t & 15;
    const int lm = t >> 2;            // 0..63
    const int lk = (t & 3) * 4;       // 0,4,8,12

    float acc[4][4] = {};

    for (int k0 = 0; k0 < K; k0 += 16) {
        __syncthreads();
        {   // stage A tile (transposed into [k][m])
            int row = m0 + lm;
            float4 v = make_float4(0.f, 0.f, 0.f, 0.f);
            if (row < M) {
                if (ABF16) {
                    const ushort4 u = *reinterpret_cast<const ushort4*>(
                        reinterpret_cast<const unsigned short*>(Ap) + (size_t)row * K + k0 + lk);
                    v.x = bf2f(u.x); v.y = bf2f(u.y); v.z = bf2f(u.z); v.w = bf2f(u.w);
                } else {
                    v = *reinterpret_cast<const float4*>(
                        reinterpret_cast<const float*>(Ap) + (size_t)row * K + k0 + lk);
                }
            }
            as[lk + 0][lm] = v.x; as[lk + 1][lm] = v.y; as[lk + 2][lm] = v.z; as[lk + 3][lm] = v.w;
        }
        {   // stage W tile (transposed into [k][n])
            const float4 v = *reinterpret_cast<const float4*>(W + (size_t)(n0 + lm) * K + k0 + lk);
            bs[lk + 0][lm] = v.x; bs[lk + 1][lm] = v.y; bs[lk + 2][lm] = v.z; bs[lk + 3][lm] = v.w;
        }
        __syncthreads();
        #pragma unroll
        for (int kk = 0; kk < 16; ++kk) {
            const float4 a4 = *reinterpret_cast<const float4*>(&as[kk][ty * 4]);
            const float4 b4 = *reinterpret_cast<const float4*>(&bs[kk][tx * 4]);
            float av[4] = {a4.x, a4.y, a4.z, a4.w};
            float bv[4] = {b4.x, b4.y, b4.z, b4.w};
            #pragma unroll
            for (int i = 0; i < 4; ++i)
                #pragma unroll
                for (int j = 0; j < 4; ++j)
                    acc[i][j] += av[i] * bv[j];
        }
    }

    #pragma unroll
    for (int i = 0; i < 4; ++i) {
        int row = m0 + ty * 4 + i;
        if (row >= M) continue;
        size_t g;
        if (ROWMAP) {
            int ib = row >> 11, j = row & 2047;          // B = 2048
            g = (size_t)ib * BP1 + 1 + j;
        } else {
            g = (size_t)row;
        }
        #pragma unroll
        for (int j = 0; j < 4; ++j) {
            int col = n0 + tx * 4 + j;
            float v = acc[i][j];
            if (BIAS1D) v += bias[col];
            if (BIAS2D) v += bias[g * NC + col];
            if (GELU)   v = 0.5f * v * (1.0f + erff(v * 0.70710678118654752f));
            size_t oi = g * NC + col;
            if (OBF16) {
                reinterpret_cast<bf16*>(Op)[oi] = __float2bfloat16(v);
            } else {
                float* O = reinterpret_cast<float*>(Op);
                if (RESID) v += O[oi];
                O[oi] = v;
            }
        }
    }
}

// ---------------- split-bf16 MFMA GEMM (round-4 verbatim, UNDER TEST) ----------------
template<int ASRC>
__global__ __launch_bounds__(256) void mm_k(const void* __restrict__ Ap,
                                            const float* __restrict__ W,
                                            void* __restrict__ Op,
                                            const float* __restrict__ bias,
                                            const float* __restrict__ rsa,
                                            int M, int K, int NC, int flags) {
    __shared__ __align__(16) short Ah[128 * 40];
    __shared__ __align__(16) short Al[128 * 40];
    __shared__ __align__(16) short Bh[128 * 40];
    __shared__ __align__(16) short Bl[128 * 40];
    const int t = threadIdx.x;
    const int m0 = blockIdx.x * 128, n0 = blockIdx.y * 128;
    const int wid = t >> 6, l = t & 63;
    const int wr = wid >> 1, wc = wid & 1;

    f32x4 acc[4][4];
    #pragma unroll
    for (int i = 0; i < 4; ++i)
        #pragma unroll
        for (int j = 0; j < 4; ++j) acc[i][j] = (f32x4)(0.0f);

    for (int k0 = 0; k0 < K; k0 += 32) {
        if (ASRC == 0) {
            const uint* A32 = (const uint*)Ap;
            #pragma unroll
            for (int q = 0; q < 4; ++q) {
                int row = q * 32 + (t >> 3);
                int kk = (t & 7) * 4;
                int grow = m0 + row; if (grow >= M) grow = M - 1;
                uint4 u = *reinterpret_cast<const uint4*>(&A32[(size_t)grow * K + k0 + kk]);
                uint h01 = (u.x >> 16) | (u.y & 0xffff0000u);
                uint h23 = (u.z >> 16) | (u.w & 0xffff0000u);
                uint l01 = (u.x & 0xffffu) | (u.y << 16);
                uint l23 = (u.z & 0xffffu) | (u.w << 16);
                *reinterpret_cast<uint2*>(&Ah[row * 40 + kk]) = make_uint2(h01, h23);
                *reinterpret_cast<uint2*>(&Al[row * 40 + kk]) = make_uint2(l01, l23);
            }
        } else {
            const unsigned short* Ab = (const unsigned short*)Ap;
            #pragma unroll
            for (int q = 0; q < 2; ++q) {
                int row = q * 64 + (t >> 2);
                int kk = (t & 3) * 8;
                int grow = m0 + row; if (grow >= M) grow = M - 1;
                uint4 u = *reinterpret_cast<const uint4*>(&Ab[(size_t)grow * K + k0 + kk]);
                *reinterpret_cast<uint4*>(&Ah[row * 40 + kk]) = u;
            }
        }
        #pragma unroll
        for (int q = 0; q < 4; ++q) {
            int row = q * 32 + (t >> 3);
            int kk = (t & 7) * 4;
            float4 f = *reinterpret_cast<const float4*>(&W[(size_t)(n0 + row) * K + k0 + kk]);
            unsigned short h0 = f2b(f.x), h1 = f2b(f.y), h2 = f2b(f.z), h3 = f2b(f.w);
            unsigned short l0 = f2b(f.x - bf2f(h0)), l1 = f2b(f.y - bf2f(h1));
            unsigned short l2 = f2b(f.z - bf2f(h2)), l3 = f2b(f.w - bf2f(h3));
            *reinterpret_cast<uint2*>(&Bh[row * 40 + kk]) =
                make_uint2((uint)h0 | ((uint)h1 << 16), (uint)h2 | ((uint)h3 << 16));
            *reinterpret_cast<uint2*>(&Bl[row * 40 + kk]) =
                make_uint2((uint)l0 | ((uint)l1 << 16), (uint)l2 | ((uint)l3 << 16));
        }
        __syncthreads();
        short8 ah[4], al[4], bh[4], bl[4];
        #pragma unroll
        for (int i = 0; i < 4; ++i) {
            int ro = (wr * 64 + i * 16 + (l & 15)) * 40 + (l >> 4) * 8;
            ah[i] = *reinterpret_cast<const short8*>(&Ah[ro]);
            if (ASRC == 0) al[i] = *reinterpret_cast<const short8*>(&Al[ro]);
        }
        #pragma unroll
        for (int j = 0; j < 4; ++j) {
            int ro = (wc * 64 + j * 16 + (l & 15)) * 40 + (l >> 4) * 8;
            bh[j] = *reinterpret_cast<const short8*>(&Bh[ro]);
            bl[j] = *reinterpret_cast<const short8*>(&Bl[ro]);
        }
        #pragma unroll
        for (int i = 0; i < 4; ++i)
            #pragma unroll
            for (int j = 0; j < 4; ++j) {
                acc[i][j] = __builtin_amdgcn_mfma_f32_16x16x32_bf16(ah[i], bh[j], acc[i][j], 0, 0, 0);
                acc[i][j] = __builtin_amdgcn_mfma_f32_16x16x32_bf16(ah[i], bl[j], acc[i][j], 0, 0, 0);
                if (ASRC == 0)
                    acc[i][j] = __builtin_amdgcn_mfma_f32_16x16x32_bf16(al[i], bh[j], acc[i][j], 0, 0, 0);
            }
        __syncthreads();
    }

    #pragma unroll
    for (int i = 0; i < 4; ++i)
        #pragma unroll
        for (int j = 0; j < 4; ++j) {
            int colb = n0 + wc * 64 + j * 16 + (l & 15);
            #pragma unroll
            for (int r = 0; r < 4; ++r) {
                int row = m0 + wr * 64 + i * 16 + (l >> 4) * 4 + r;
                if (row >= M) continue;
                float v = acc[i][j][r];
                size_t g = (flags & F_ROWMAP) ? ((size_t)(row >> 11) * BP1 + 1 + (row & 2047))
                                             : (size_t)row;
                if (flags & F_RSAE)   v *= rsa[g * 8 + (colb >> 5)];
                if (flags & F_BIAS1D) v += bias[colb];
                if (flags & F_BIAS2D) v += bias[g * (size_t)NC + colb];
                if (flags & F_GELU)   v = 0.5f * v * (1.0f + erff(v * 0.70710678118654752f));
                size_t oi = g * (size_t)NC + colb;
                if (flags & F_OUTB16) {
                    reinterpret_cast<unsigned short*>(Op)[oi] = f2b(v);
                } else {
                    float* O = reinterpret_cast<float*>(Op);
                    if (flags & F_RESID) v += O[oi];
                    O[oi] = v;
                }
            }
        }
}

// ---------------- launch ----------------
extern "C" void kernel_launch(void* const* d_in, const int* in_sizes, int n_in,
                              void* d_out, int out_size, void* d_ws, size_t ws_size,
                              hipStream_t stream) {
    const float* x      = (const float*)d_in[0];
    const float* weight = (const float*)d_in[1];
    const float* bias   = (const float*)d_in[2];
    const float* cls    = (const float*)d_in[3];
    const float* Wqkv   = (const float*)d_in[4];
    const float* Wo     = (const float*)d_in[5];
    const float* ln1_g  = (const float*)d_in[6];
    const float* ln1_b  = (const float*)d_in[7];
    const float* ln2_g  = (const float*)d_in[8];
    const float* ln2_b  = (const float*)d_in[9];
    const float* fc1_w  = (const float*)d_in[10];
    const float* fc1_b  = (const float*)d_in[11];
    const float* fc2_w  = (const float*)d_in[12];
    const float* fc2_b  = (const float*)d_in[13];
    float* out = (float*)d_out;

    // round-1 proven workspace layout (high-water 204,046,336 B)
    char* ws = (char*)d_ws;
    float* z    = (float*)(ws + 0);
    uint*  zpk  = (uint*)(ws + 0);                            // packed-x alias (pre-ln phase)
    float* imv  = (float*)(ws + 67141632);
    bf16*  hbuf = (bf16*) (ws + 67141632);                    // spans imv+spare
    float* wt   = (float*)(ws + 201424896);
    float* tot  = (float*)(ws + 203784192);

    // ---- mm_k probes (outputs into regions overwritten before any read) ----
    // probe A: ASRC=1 path + BIAS1D + GELU, x reinterpreted as bf16, dump -> imv region
    mm_k<1><<<dim3(128, 2), 256, 0, stream>>>((const void*)x, fc2_w, imv, fc2_b, nullptr,
                                              16384, FFN, CC, F_BIAS1D | F_GELU);
    // pack x -> z region (consumed by the real embed mm_k below, then ln_k overwrites)
    pack_k<<<65536, 256, 0, stream>>>(x, zpk, AA * BB * CC);
    // probe B: ASRC=0 path + BIAS1D + GELU + OUTB16, dump -> imv region (bf16)
    mm_k<0><<<dim3(128, 8), 256, 0, stream>>>(zpk, fc1_w, imv, fc1_b, nullptr,
                                              16384, CC, FFN, F_BIAS1D | F_GELU | F_OUTB16);

    row0_k<<<AA, 256, 0, stream>>>(out, cls, bias);
    // REAL embed via mm_k (validates split-bf16 numerics + rowmap + bias2d end-to-end)
    mm_k<0><<<dim3(512, 2), 256, 0, stream>>>(zpk, weight, out, bias, nullptr,
                                              AA * BB, CC, CC, F_ROWMAP | F_BIAS2D);
    wqkv_t_k<<<2304, 256, 0, stream>>>(Wqkv, wt);

    for (int a = 0; a < NBLK; ++a) {
        ln_k<<<NROWS / 4, 256, 0, stream>>>(out, z, ln1_g, ln1_b);
        qkv_k<<<NROWS / 32, 256, 0, stream>>>(z, wt + (size_t)a * 8 * 256 * 96, imv);
        cumsum1_k<<<256, 256, 0, stream>>>(imv, tot);
        cumsum2_k<<<256, 256, 0, stream>>>(imv, tot);
        gemm_k<false,false,false,false,false,true,false>
            <<<dim3(1025, 4), 256, 0, stream>>>(imv, Wo + (size_t)a * CC * CC, out, nullptr, NROWS, CC, CC);
        ln_k<<<NROWS / 4, 256, 0, stream>>>(out, z, ln2_g, ln2_b);
        gemm_k<false,true,false,false,true,false,true>
            <<<dim3(1025, 16), 256, 0, stream>>>(z, fc1_w, hbuf, fc1_b, NROWS, CC, FFN);
        gemm_k<true,false,false,false,true,true,false>
            <<<dim3(1025, 4), 256, 0, stream>>>(hbuf, fc2_w, out, fc2_b, NROWS, FFN, CC);
    }
}

// Round 6
// 3357.187 us; speedup vs baseline: 1.7847x; 1.7847x over previous
//
#include <hip/hip_runtime.h>
#include <math.h>

#define AA 32
#define BB 2048
#define BP1 2049
#define CC 256
#define NROWS (AA * BP1)          // 65568
#define NBLK 3
#define FFN 1024

typedef unsigned int uint;
typedef __attribute__((ext_vector_type(4))) float f32x4;
typedef __attribute__((ext_vector_type(8))) short short8;

// epilogue flag bits for mm_k (wave-uniform runtime flags)
#define F_RSAE   1
#define F_ROWMAP 2
#define F_BIAS2D 4
#define F_BIAS1D 8
#define F_GELU   16
#define F_RESID  32
#define F_OUTB16 64

__device__ __forceinline__ float bf2f(unsigned short u) {
    return __uint_as_float(((unsigned int)u) << 16);
}
__device__ __forceinline__ unsigned short f2b(float x) {   // fp32 -> bf16 RNE
    uint u = __float_as_uint(x);
    u += 0x7fff + ((u >> 16) & 1);
    return (unsigned short)(u >> 16);
}
__device__ __forceinline__ uint packsplit(float x) {       // {hi16, lo16}
    unsigned short h = f2b(x);
    unsigned short l = f2b(x - bf2f(h));
    return (((uint)h) << 16) | (uint)l;
}

// ---------------- fp32 -> packed split ----------------
__global__ __launch_bounds__(256) void pack_k(const float* __restrict__ src,
                                              uint* __restrict__ dst, int n) {
    int i = blockIdx.x * 256 + threadIdx.x;
    if (i < n) dst[i] = packsplit(src[i]);
}

// ---------------- row 0 of each batch: cls + bias ----------------
__global__ __launch_bounds__(256) void row0_k(float* __restrict__ out,
                                              const float* __restrict__ cls,
                                              const float* __restrict__ bias) {
    int i = blockIdx.x, t = threadIdx.x;
    size_t o = (size_t)i * BP1 * CC + t;
    out[o] = cls[i * CC + t] + bias[o];
}

// ---------------- layernorm f32 (proven) ----------------
__global__ __launch_bounds__(256) void ln_k(const float* __restrict__ in, float* __restrict__ out,
                                            const float* __restrict__ g, const float* __restrict__ b) {
    int row = blockIdx.x * 4 + (threadIdx.x >> 6);
    int lane = threadIdx.x & 63;
    const float4 v = *reinterpret_cast<const float4*>(in + (size_t)row * CC + lane * 4);
    float s = v.x + v.y + v.z + v.w;
    float sq = v.x * v.x + v.y * v.y + v.z * v.z + v.w * v.w;
    #pragma unroll
    for (int m = 1; m < 64; m <<= 1) { s += __shfl_xor(s, m); sq += __shfl_xor(sq, m); }
    float mu = s * (1.0f / CC);
    float var = sq * (1.0f / CC) - mu * mu;
    float rs = rsqrtf(var + 1e-5f);
    const float4 gg = *reinterpret_cast<const float4*>(g + lane * 4);
    const float4 bb = *reinterpret_cast<const float4*>(b + lane * 4);
    float4 o;
    o.x = (v.x - mu) * rs * gg.x + bb.x;
    o.y = (v.y - mu) * rs * gg.y + bb.y;
    o.z = (v.z - mu) * rs * gg.z + bb.z;
    o.w = (v.w - mu) * rs * gg.w + bb.w;
    *reinterpret_cast<float4*>(out + (size_t)row * CC + lane * 4) = o;
}

// ---------------- rsa[r][h] = (q.k)/sqrt(32) ----------------
__global__ __launch_bounds__(256) void rsa_k(const float* __restrict__ qb,
                                             const float* __restrict__ kb,
                                             float* __restrict__ rsa) {
    int row = blockIdx.x * 4 + (threadIdx.x >> 6);
    int l = threadIdx.x & 63;
    const float4 q4 = *reinterpret_cast<const float4*>(qb + (size_t)row * CC + l * 4);
    const float4 k4 = *reinterpret_cast<const float4*>(kb + (size_t)row * CC + l * 4);
    float p = q4.x * k4.x + q4.y * k4.y + q4.z * k4.z + q4.w * k4.w;
    p += __shfl_xor(p, 1); p += __shfl_xor(p, 2); p += __shfl_xor(p, 4);
    if ((l & 7) == 0) rsa[(size_t)row * 8 + (l >> 3)] = p * 0.17677669529663689f;
}

// ---------------- cumsum f32 (round-1 proven) ----------------
__global__ __launch_bounds__(256) void cumsum1_k(float* __restrict__ imv, float* __restrict__ tot) {
    int i = blockIdx.x >> 3, ch = blockIdx.x & 7, c = threadIdx.x;
    size_t base = ((size_t)i * BP1 + ch * 256) * CC + c;
    float acc = 0.f;
    for (int j = 0; j < 256; ++j) {
        acc += imv[base + (size_t)j * CC];
        imv[base + (size_t)j * CC] = acc;
    }
    tot[((size_t)i * 8 + ch) * CC + c] = acc;
}

__global__ __launch_bounds__(256) void cumsum2_k(float* __restrict__ imv, const float* __restrict__ tot) {
    int i = blockIdx.x >> 3, ch = blockIdx.x & 7, c = threadIdx.x;
    if (ch == 0) return;
    float off = 0.f;
    for (int p = 0; p < ch; ++p) off += tot[((size_t)i * 8 + p) * CC + c];
    size_t base = ((size_t)i * BP1 + ch * 256) * CC + c;
    for (int j = 0; j < 256; ++j) imv[base + (size_t)j * CC] += off;
}

// ---------------- split-bf16 MFMA GEMM: Out(MxN) = A(MxK) * W(NxK)^T ----------------
// ASRC: 0 = packed-split uint32 A, 1 = plain bf16 A (no lo term), 2 = fp32 A (split at staging)
// W is raw fp32 [NC][K], split at staging (weights are small & L2-resident).
template<int ASRC>
__global__ __launch_bounds__(256) void mm_k(const void* __restrict__ Ap,
                                            const float* __restrict__ W,
                                            void* __restrict__ Op,
                                            const float* __restrict__ bias,
                                            const float* __restrict__ rsa,
                                            int M, int K, int NC, int flags) {
    __shared__ __align__(16) short Ah[128 * 40];
    __shared__ __align__(16) short Al[128 * 40];
    __shared__ __align__(16) short Bh[128 * 40];
    __shared__ __align__(16) short Bl[128 * 40];
    const int t = threadIdx.x;
    const int m0 = blockIdx.x * 128, n0 = blockIdx.y * 128;
    const int wid = t >> 6, l = t & 63;
    const int wr = wid >> 1, wc = wid & 1;

    f32x4 acc[4][4];
    #pragma unroll
    for (int i = 0; i < 4; ++i)
        #pragma unroll
        for (int j = 0; j < 4; ++j) acc[i][j] = (f32x4)(0.0f);

    for (int k0 = 0; k0 < K; k0 += 32) {
        if (ASRC == 0) {
            const uint* A32 = (const uint*)Ap;
            #pragma unroll
            for (int q = 0; q < 4; ++q) {
                int row = q * 32 + (t >> 3);
                int kk = (t & 7) * 4;
                int grow = m0 + row; if (grow >= M) grow = M - 1;
                uint4 u = *reinterpret_cast<const uint4*>(&A32[(size_t)grow * K + k0 + kk]);
                uint h01 = (u.x >> 16) | (u.y & 0xffff0000u);
                uint h23 = (u.z >> 16) | (u.w & 0xffff0000u);
                uint l01 = (u.x & 0xffffu) | (u.y << 16);
                uint l23 = (u.z & 0xffffu) | (u.w << 16);
                *reinterpret_cast<uint2*>(&Ah[row * 40 + kk]) = make_uint2(h01, h23);
                *reinterpret_cast<uint2*>(&Al[row * 40 + kk]) = make_uint2(l01, l23);
            }
        } else if (ASRC == 1) {
            const unsigned short* Ab = (const unsigned short*)Ap;
            #pragma unroll
            for (int q = 0; q < 2; ++q) {
                int row = q * 64 + (t >> 2);
                int kk = (t & 3) * 8;
                int grow = m0 + row; if (grow >= M) grow = M - 1;
                uint4 u = *reinterpret_cast<const uint4*>(&Ab[(size_t)grow * K + k0 + kk]);
                *reinterpret_cast<uint4*>(&Ah[row * 40 + kk]) = u;
            }
        } else {
            const float* Af = (const float*)Ap;
            #pragma unroll
            for (int q = 0; q < 4; ++q) {
                int row = q * 32 + (t >> 3);
                int kk = (t & 7) * 4;
                int grow = m0 + row; if (grow >= M) grow = M - 1;
                float4 f = *reinterpret_cast<const float4*>(&Af[(size_t)grow * K + k0 + kk]);
                unsigned short h0 = f2b(f.x), h1 = f2b(f.y), h2 = f2b(f.z), h3 = f2b(f.w);
                unsigned short l0 = f2b(f.x - bf2f(h0)), l1 = f2b(f.y - bf2f(h1));
                unsigned short l2 = f2b(f.z - bf2f(h2)), l3 = f2b(f.w - bf2f(h3));
                *reinterpret_cast<uint2*>(&Ah[row * 40 + kk]) =
                    make_uint2((uint)h0 | ((uint)h1 << 16), (uint)h2 | ((uint)h3 << 16));
                *reinterpret_cast<uint2*>(&Al[row * 40 + kk]) =
                    make_uint2((uint)l0 | ((uint)l1 << 16), (uint)l2 | ((uint)l3 << 16));
            }
        }
        #pragma unroll
        for (int q = 0; q < 4; ++q) {
            int row = q * 32 + (t >> 3);
            int kk = (t & 7) * 4;
            float4 f = *reinterpret_cast<const float4*>(&W[(size_t)(n0 + row) * K + k0 + kk]);
            unsigned short h0 = f2b(f.x), h1 = f2b(f.y), h2 = f2b(f.z), h3 = f2b(f.w);
            unsigned short l0 = f2b(f.x - bf2f(h0)), l1 = f2b(f.y - bf2f(h1));
            unsigned short l2 = f2b(f.z - bf2f(h2)), l3 = f2b(f.w - bf2f(h3));
            *reinterpret_cast<uint2*>(&Bh[row * 40 + kk]) =
                make_uint2((uint)h0 | ((uint)h1 << 16), (uint)h2 | ((uint)h3 << 16));
            *reinterpret_cast<uint2*>(&Bl[row * 40 + kk]) =
                make_uint2((uint)l0 | ((uint)l1 << 16), (uint)l2 | ((uint)l3 << 16));
        }
        __syncthreads();
        short8 ah[4], al[4], bh[4], bl[4];
        #pragma unroll
        for (int i = 0; i < 4; ++i) {
            int ro = (wr * 64 + i * 16 + (l & 15)) * 40 + (l >> 4) * 8;
            ah[i] = *reinterpret_cast<const short8*>(&Ah[ro]);
            if (ASRC != 1) al[i] = *reinterpret_cast<const short8*>(&Al[ro]);
        }
        #pragma unroll
        for (int j = 0; j < 4; ++j) {
            int ro = (wc * 64 + j * 16 + (l & 15)) * 40 + (l >> 4) * 8;
            bh[j] = *reinterpret_cast<const short8*>(&Bh[ro]);
            bl[j] = *reinterpret_cast<const short8*>(&Bl[ro]);
        }
        #pragma unroll
        for (int i = 0; i < 4; ++i)
            #pragma unroll
            for (int j = 0; j < 4; ++j) {
                acc[i][j] = __builtin_amdgcn_mfma_f32_16x16x32_bf16(ah[i], bh[j], acc[i][j], 0, 0, 0);
                acc[i][j] = __builtin_amdgcn_mfma_f32_16x16x32_bf16(ah[i], bl[j], acc[i][j], 0, 0, 0);
                if (ASRC != 1)
                    acc[i][j] = __builtin_amdgcn_mfma_f32_16x16x32_bf16(al[i], bh[j], acc[i][j], 0, 0, 0);
            }
        __syncthreads();
    }

    #pragma unroll
    for (int i = 0; i < 4; ++i)
        #pragma unroll
        for (int j = 0; j < 4; ++j) {
            int colb = n0 + wc * 64 + j * 16 + (l & 15);
            #pragma unroll
            for (int r = 0; r < 4; ++r) {
                int row = m0 + wr * 64 + i * 16 + (l >> 4) * 4 + r;
                if (row >= M) continue;
                float v = acc[i][j][r];
                size_t g = (flags & F_ROWMAP) ? ((size_t)(row >> 11) * BP1 + 1 + (row & 2047))
                                             : (size_t)row;
                if (flags & F_RSAE)   v *= rsa[g * 8 + (colb >> 5)];
                if (flags & F_BIAS1D) v += bias[colb];
                if (flags & F_BIAS2D) v += bias[g * (size_t)NC + colb];
                if (flags & F_GELU)   v = 0.5f * v * (1.0f + erff(v * 0.70710678118654752f));
                size_t oi = g * (size_t)NC + colb;
                if (flags & F_OUTB16) {
                    reinterpret_cast<unsigned short*>(Op)[oi] = f2b(v);
                } else {
                    float* O = reinterpret_cast<float*>(Op);
                    if (flags & F_RESID) v += O[oi];
                    O[oi] = v;
                }
            }
        }
}

// ---------------- launch ----------------
extern "C" void kernel_launch(void* const* d_in, const int* in_sizes, int n_in,
                              void* d_out, int out_size, void* d_ws, size_t ws_size,
                              hipStream_t stream) {
    const float* x      = (const float*)d_in[0];
    const float* weight = (const float*)d_in[1];
    const float* bias   = (const float*)d_in[2];
    const float* cls    = (const float*)d_in[3];
    const float* Wqkv   = (const float*)d_in[4];
    const float* Wo     = (const float*)d_in[5];
    const float* ln1_g  = (const float*)d_in[6];
    const float* ln1_b  = (const float*)d_in[7];
    const float* ln2_g  = (const float*)d_in[8];
    const float* ln2_b  = (const float*)d_in[9];
    const float* fc1_w  = (const float*)d_in[10];
    const float* fc1_b  = (const float*)d_in[11];
    const float* fc2_w  = (const float*)d_in[12];
    const float* fc2_b  = (const float*)d_in[13];
    float* out = (float*)d_out;

    // ---- workspace (max offset 203,785,216 < 204,046,336 proven) ----
    // R0 [0,           67,141,632)  z f32 (live as ASRC=2 A operand)
    // R1 [67,141,632, 134,283,264)  qbuf f32 -> imv f32 -> hbuf lo half
    // R2 [134,283,264,201,424,896)  kbuf f32 -> impk u32 -> hbuf hi half
    // rsa [201,424,896,203,523,072) NROWS*8 f32
    // tot [203,523,072,203,785,216) 32*8*256 f32
    char* ws = (char*)d_ws;
    float* z    = (float*)(ws + 0);
    float* qbuf = (float*)(ws + 67141632);
    float* imv  = (float*)(ws + 67141632);                    // overlays qbuf
    float* kbuf = (float*)(ws + 134283264);
    uint*  impk = (uint*) (ws + 134283264);                   // overlays kbuf
    unsigned short* hbuf = (unsigned short*)(ws + 67141632);  // spans R1+R2
    float* rsa  = (float*)(ws + 201424896);
    float* tot  = (float*)(ws + 203523072);

    row0_k<<<AA, 256, 0, stream>>>(out, cls, bias);
    // embed: out[i,1+j,:] = x[i,j,:] @ weight^T + bias  (A = x fp32 directly)
    mm_k<2><<<dim3(512, 2), 256, 0, stream>>>(x, weight, out, bias, nullptr,
                                              AA * BB, CC, CC, F_ROWMAP | F_BIAS2D);

    const int MT = (NROWS + 127) / 128;   // 513
    for (int a = 0; a < NBLK; ++a) {
        // Wqkv is (TK=3, 3, HA, DH, C): per-a stride 3*8*32*256 = 196608, x-stride 65536
        const float* wq = Wqkv + (size_t)a * 196608;
        ln_k<<<NROWS / 4, 256, 0, stream>>>(out, z, ln1_g, ln1_b);
        mm_k<2><<<dim3(MT, 2), 256, 0, stream>>>(z, wq,          qbuf, nullptr, nullptr,
                                                 NROWS, CC, CC, 0);
        mm_k<2><<<dim3(MT, 2), 256, 0, stream>>>(z, wq + 65536,  kbuf, nullptr, nullptr,
                                                 NROWS, CC, CC, 0);
        rsa_k<<<NROWS / 4, 256, 0, stream>>>(qbuf, kbuf, rsa);
        // v-gemm with rsa scaling -> imv (overlays qbuf, consumed by rsa_k)
        mm_k<2><<<dim3(MT, 2), 256, 0, stream>>>(z, wq + 131072, imv, nullptr, rsa,
                                                 NROWS, CC, CC, F_RSAE);
        cumsum1_k<<<256, 256, 0, stream>>>(imv, tot);
        cumsum2_k<<<256, 256, 0, stream>>>(imv, tot);
        // pack imv -> impk (kbuf dead after rsa_k)
        pack_k<<<65568, 256, 0, stream>>>(imv, impk, NROWS * CC);
        // savespace += impk @ Wo[a]^T
        mm_k<0><<<dim3(MT, 2), 256, 0, stream>>>(impk, Wo + (size_t)a * 65536, out,
                                                 nullptr, nullptr, NROWS, CC, CC, F_RESID);
        ln_k<<<NROWS / 4, 256, 0, stream>>>(out, z, ln2_g, ln2_b);
        // h = gelu(z @ fc1_w^T + fc1_b) -> bf16 spanning R1+R2 (imv/impk dead)
        mm_k<2><<<dim3(MT, 8), 256, 0, stream>>>(z, fc1_w, hbuf, fc1_b, nullptr,
                                                 NROWS, CC, FFN, F_BIAS1D | F_GELU | F_OUTB16);
        // savespace += h @ fc2_w^T + fc2_b
        mm_k<1><<<dim3(MT, 2), 256, 0, stream>>>(hbuf, fc2_w, out, fc2_b, nullptr,
                                                 NROWS, FFN, CC, F_BIAS1D | F_RESID);
    }
}

// Round 7
// 3021.533 us; speedup vs baseline: 1.9829x; 1.1111x over previous
//
#include <hip/hip_runtime.h>
#include <math.h>

#define AA 32
#define BB 2048
#define BP1 2049
#define CC 256
#define NROWS (AA * BP1)          // 65568
#define NBLK 3
#define FFN 1024

typedef unsigned int uint;
typedef __attribute__((ext_vector_type(4))) float f32x4;
typedef __attribute__((ext_vector_type(8))) short short8;

// epilogue flag bits for mm_k (wave-uniform runtime flags)
#define F_RSAE   1
#define F_ROWMAP 2
#define F_BIAS2D 4
#define F_BIAS1D 8
#define F_GELU   16
#define F_RESID  32
#define F_OUTB16 64

__device__ __forceinline__ float bf2f(unsigned short u) {
    return __uint_as_float(((unsigned int)u) << 16);
}
__device__ __forceinline__ unsigned short f2b(float x) {   // fp32 -> bf16 RNE
    uint u = __float_as_uint(x);
    u += 0x7fff + ((u >> 16) & 1);
    return (unsigned short)(u >> 16);
}
__device__ __forceinline__ uint packsplit(float x) {       // {hi16, lo16}
    unsigned short h = f2b(x);
    unsigned short l = f2b(x - bf2f(h));
    return (((uint)h) << 16) | (uint)l;
}

// ---------------- fp32 -> packed split ----------------
__global__ __launch_bounds__(256) void pack_k(const float* __restrict__ src,
                                              uint* __restrict__ dst, int n) {
    int i = blockIdx.x * 256 + threadIdx.x;
    if (i < n) dst[i] = packsplit(src[i]);
}

// ---------------- row 0 of each batch: cls + bias ----------------
__global__ __launch_bounds__(256) void row0_k(float* __restrict__ out,
                                              const float* __restrict__ cls,
                                              const float* __restrict__ bias) {
    int i = blockIdx.x, t = threadIdx.x;
    size_t o = (size_t)i * BP1 * CC + t;
    out[o] = cls[i * CC + t] + bias[o];
}

// ---------------- layernorm f32 -> packed split ----------------
__global__ __launch_bounds__(256) void ln_k(const float* __restrict__ in, uint* __restrict__ zpk,
                                            const float* __restrict__ g, const float* __restrict__ b) {
    int row = blockIdx.x * 4 + (threadIdx.x >> 6);
    int lane = threadIdx.x & 63;
    const float4 v = *reinterpret_cast<const float4*>(in + (size_t)row * CC + lane * 4);
    float s = v.x + v.y + v.z + v.w;
    float sq = v.x * v.x + v.y * v.y + v.z * v.z + v.w * v.w;
    #pragma unroll
    for (int m = 1; m < 64; m <<= 1) { s += __shfl_xor(s, m); sq += __shfl_xor(sq, m); }
    float mu = s * (1.0f / CC);
    float var = sq * (1.0f / CC) - mu * mu;
    float rs = rsqrtf(var + 1e-5f);
    const float4 gg = *reinterpret_cast<const float4*>(g + lane * 4);
    const float4 bb = *reinterpret_cast<const float4*>(b + lane * 4);
    uint4 o;
    o.x = packsplit((v.x - mu) * rs * gg.x + bb.x);
    o.y = packsplit((v.y - mu) * rs * gg.y + bb.y);
    o.z = packsplit((v.z - mu) * rs * gg.z + bb.z);
    o.w = packsplit((v.w - mu) * rs * gg.w + bb.w);
    *reinterpret_cast<uint4*>(zpk + (size_t)row * CC + lane * 4) = o;
}

// ---------------- rsa[r][h] = (q.k)/sqrt(32) ----------------
__global__ __launch_bounds__(256) void rsa_k(const float* __restrict__ qb,
                                             const float* __restrict__ kb,
                                             float* __restrict__ rsa) {
    int row = blockIdx.x * 4 + (threadIdx.x >> 6);
    int l = threadIdx.x & 63;
    const float4 q4 = *reinterpret_cast<const float4*>(qb + (size_t)row * CC + l * 4);
    const float4 k4 = *reinterpret_cast<const float4*>(kb + (size_t)row * CC + l * 4);
    float p = q4.x * k4.x + q4.y * k4.y + q4.z * k4.z + q4.w * k4.w;
    p += __shfl_xor(p, 1); p += __shfl_xor(p, 2); p += __shfl_xor(p, 4);
    if ((l & 7) == 0) rsa[(size_t)row * 8 + (l >> 3)] = p * 0.17677669529663689f;
}

// ---------------- cumsum pass 1: per-chunk totals (read-only, 8 x 256 rows) ----------------
__global__ __launch_bounds__(256) void cumsum1_k(const float* __restrict__ imv, float* __restrict__ tot) {
    int bi = blockIdx.x >> 3, ch = blockIdx.x & 7, c = threadIdx.x;
    size_t base = ((size_t)bi * BP1 + ch * 256) * CC + c;
    float s = 0.f;
    for (int j = 0; j < 256; ++j) s += imv[base + (size_t)j * CC];
    tot[((size_t)bi * 8 + ch) * CC + c] = s;
}

// ---------------- cumsum pass 2: scan + offset, write packed split in place ----------------
__global__ __launch_bounds__(256) void cumsum2_k(uint* __restrict__ p, const float* __restrict__ tot) {
    int bi = blockIdx.x / 9, ch = blockIdx.x - bi * 9, c = threadIdx.x;
    if (ch == 8) {   // row BB (untouched by cumsum): just re-pack
        size_t idx = ((size_t)bi * BP1 + BB) * CC + c;
        p[idx] = packsplit(__uint_as_float(p[idx]));
        return;
    }
    float s = 0.f;
    for (int q = 0; q < ch; ++q) s += tot[((size_t)bi * 8 + q) * CC + c];
    size_t base = ((size_t)bi * BP1 + ch * 256) * CC + c;
    for (int j = 0; j < 256; ++j) {
        s += __uint_as_float(p[base + (size_t)j * CC]);
        p[base + (size_t)j * CC] = packsplit(s);
    }
}

// ---------------- split-bf16 MFMA GEMM: Out(MxN) = A(MxK) * W(NxK)^T ----------------
// ASRC: 0 = packed-split uint32 A, 1 = plain bf16 A (no lo term)
// WSRC: 0 = packed-split uint32 W, 1 = raw fp32 W (split at staging)
template<int ASRC, int WSRC>
__global__ __launch_bounds__(256) void mm_k(const void* __restrict__ Ap,
                                            const void* __restrict__ Wp,
                                            void* __restrict__ Op,
                                            const float* __restrict__ bias,
                                            const float* __restrict__ rsa,
                                            int M, int K, int NC, int flags) {
    __shared__ __align__(16) short Ah[128 * 40];
    __shared__ __align__(16) short Al[128 * 40];
    __shared__ __align__(16) short Bh[128 * 40];
    __shared__ __align__(16) short Bl[128 * 40];
    const int t = threadIdx.x;
    const int m0 = blockIdx.x * 128, n0 = blockIdx.y * 128;
    const int wid = t >> 6, l = t & 63;
    const int wr = wid >> 1, wc = wid & 1;

    f32x4 acc[4][4];
    #pragma unroll
    for (int i = 0; i < 4; ++i)
        #pragma unroll
        for (int j = 0; j < 4; ++j) acc[i][j] = (f32x4)(0.0f);

    for (int k0 = 0; k0 < K; k0 += 32) {
        // ---- stage A ----
        if (ASRC == 0) {
            const uint* A32 = (const uint*)Ap;
            #pragma unroll
            for (int q = 0; q < 4; ++q) {
                int row = q * 32 + (t >> 3);
                int kk = (t & 7) * 4;
                int grow = m0 + row; if (grow >= M) grow = M - 1;
                uint4 u = *reinterpret_cast<const uint4*>(&A32[(size_t)grow * K + k0 + kk]);
                uint h01 = (u.x >> 16) | (u.y & 0xffff0000u);
                uint h23 = (u.z >> 16) | (u.w & 0xffff0000u);
                uint l01 = (u.x & 0xffffu) | (u.y << 16);
                uint l23 = (u.z & 0xffffu) | (u.w << 16);
                *reinterpret_cast<uint2*>(&Ah[row * 40 + kk]) = make_uint2(h01, h23);
                *reinterpret_cast<uint2*>(&Al[row * 40 + kk]) = make_uint2(l01, l23);
            }
        } else {
            const unsigned short* Ab = (const unsigned short*)Ap;
            #pragma unroll
            for (int q = 0; q < 2; ++q) {
                int row = q * 64 + (t >> 2);
                int kk = (t & 3) * 8;
                int grow = m0 + row; if (grow >= M) grow = M - 1;
                uint4 u = *reinterpret_cast<const uint4*>(&Ab[(size_t)grow * K + k0 + kk]);
                *reinterpret_cast<uint4*>(&Ah[row * 40 + kk]) = u;
            }
        }
        // ---- stage B ----
        if (WSRC == 0) {
            const uint* W32 = (const uint*)Wp;
            #pragma unroll
            for (int q = 0; q < 4; ++q) {
                int row = q * 32 + (t >> 3);
                int kk = (t & 7) * 4;
                uint4 u = *reinterpret_cast<const uint4*>(&W32[(size_t)(n0 + row) * K + k0 + kk]);
                uint h01 = (u.x >> 16) | (u.y & 0xffff0000u);
                uint h23 = (u.z >> 16) | (u.w & 0xffff0000u);
                uint l01 = (u.x & 0xffffu) | (u.y << 16);
                uint l23 = (u.z & 0xffffu) | (u.w << 16);
                *reinterpret_cast<uint2*>(&Bh[row * 40 + kk]) = make_uint2(h01, h23);
                *reinterpret_cast<uint2*>(&Bl[row * 40 + kk]) = make_uint2(l01, l23);
            }
        } else {
            const float* Wf = (const float*)Wp;
            #pragma unroll
            for (int q = 0; q < 4; ++q) {
                int row = q * 32 + (t >> 3);
                int kk = (t & 7) * 4;
                float4 f = *reinterpret_cast<const float4*>(&Wf[(size_t)(n0 + row) * K + k0 + kk]);
                unsigned short h0 = f2b(f.x), h1 = f2b(f.y), h2 = f2b(f.z), h3 = f2b(f.w);
                unsigned short l0 = f2b(f.x - bf2f(h0)), l1 = f2b(f.y - bf2f(h1));
                unsigned short l2 = f2b(f.z - bf2f(h2)), l3 = f2b(f.w - bf2f(h3));
                *reinterpret_cast<uint2*>(&Bh[row * 40 + kk]) =
                    make_uint2((uint)h0 | ((uint)h1 << 16), (uint)h2 | ((uint)h3 << 16));
                *reinterpret_cast<uint2*>(&Bl[row * 40 + kk]) =
                    make_uint2((uint)l0 | ((uint)l1 << 16), (uint)l2 | ((uint)l3 << 16));
            }
        }
        __syncthreads();
        // ---- fragments + MFMA ----
        short8 ah[4], al[4], bh[4], bl[4];
        #pragma unroll
        for (int i = 0; i < 4; ++i) {
            int ro = (wr * 64 + i * 16 + (l & 15)) * 40 + (l >> 4) * 8;
            ah[i] = *reinterpret_cast<const short8*>(&Ah[ro]);
            if (ASRC == 0) al[i] = *reinterpret_cast<const short8*>(&Al[ro]);
        }
        #pragma unroll
        for (int j = 0; j < 4; ++j) {
            int ro = (wc * 64 + j * 16 + (l & 15)) * 40 + (l >> 4) * 8;
            bh[j] = *reinterpret_cast<const short8*>(&Bh[ro]);
            bl[j] = *reinterpret_cast<const short8*>(&Bl[ro]);
        }
        #pragma unroll
        for (int i = 0; i < 4; ++i)
            #pragma unroll
            for (int j = 0; j < 4; ++j) {
                acc[i][j] = __builtin_amdgcn_mfma_f32_16x16x32_bf16(ah[i], bh[j], acc[i][j], 0, 0, 0);
                acc[i][j] = __builtin_amdgcn_mfma_f32_16x16x32_bf16(ah[i], bl[j], acc[i][j], 0, 0, 0);
                if (ASRC == 0)
                    acc[i][j] = __builtin_amdgcn_mfma_f32_16x16x32_bf16(al[i], bh[j], acc[i][j], 0, 0, 0);
            }
        __syncthreads();
    }

    // ---- epilogue (runtime flags, wave-uniform) ----
    #pragma unroll
    for (int i = 0; i < 4; ++i)
        #pragma unroll
        for (int j = 0; j < 4; ++j) {
            int colb = n0 + wc * 64 + j * 16 + (l & 15);
            #pragma unroll
            for (int r = 0; r < 4; ++r) {
                int row = m0 + wr * 64 + i * 16 + (l >> 4) * 4 + r;
                if (row >= M) continue;
                float v = acc[i][j][r];
                size_t g = (flags & F_ROWMAP) ? ((size_t)(row >> 11) * BP1 + 1 + (row & 2047))
                                             : (size_t)row;
                if (flags & F_RSAE)   v *= rsa[g * 8 + (colb >> 5)];
                if (flags & F_BIAS1D) v += bias[colb];
                if (flags & F_BIAS2D) v += bias[g * (size_t)NC + colb];
                if (flags & F_GELU)   v = 0.5f * v * (1.0f + erff(v * 0.70710678118654752f));
                size_t oi = g * (size_t)NC + colb;
                if (flags & F_OUTB16) {
                    reinterpret_cast<unsigned short*>(Op)[oi] = f2b(v);
                } else {
                    float* O = reinterpret_cast<float*>(Op);
                    if (flags & F_RESID) v += O[oi];
                    O[oi] = v;
                }
            }
        }
}

// ---------------- launch ----------------
extern "C" void kernel_launch(void* const* d_in, const int* in_sizes, int n_in,
                              void* d_out, int out_size, void* d_ws, size_t ws_size,
                              hipStream_t stream) {
    const float* x      = (const float*)d_in[0];
    const float* weight = (const float*)d_in[1];
    const float* bias   = (const float*)d_in[2];
    const float* cls    = (const float*)d_in[3];
    const float* Wqkv   = (const float*)d_in[4];
    const float* Wo     = (const float*)d_in[5];
    const float* ln1_g  = (const float*)d_in[6];
    const float* ln1_b  = (const float*)d_in[7];
    const float* ln2_g  = (const float*)d_in[8];
    const float* ln2_b  = (const float*)d_in[9];
    const float* fc1_w  = (const float*)d_in[10];
    const float* fc1_b  = (const float*)d_in[11];
    const float* fc2_w  = (const float*)d_in[12];
    const float* fc2_b  = (const float*)d_in[13];
    float* out = (float*)d_out;

    // ---- workspace ----
    // zpk  [0,           67,141,632)  u32: packed x, then packed z
    // R1   [67,141,632, 134,283,264)  qbuf f32 -> imv f32 (packed in place) -> hbuf lo
    // R2   [134,283,264,201,424,896)  kbuf f32 -> hbuf hi
    // rsa  [201,424,896,203,523,072)
    // tot  [203,523,072,203,785,216)
    // wpk  [203,785,216,209,290,240)  packed weights (only if ws_size allows)
    char* ws = (char*)d_ws;
    uint*  zpk  = (uint*)(ws + 0);
    float* qbuf = (float*)(ws + 67141632);
    float* imv  = (float*)(ws + 67141632);                    // overlays qbuf
    float* kbuf = (float*)(ws + 134283264);
    unsigned short* hbuf = (unsigned short*)(ws + 67141632);  // spans R1+R2
    float* rsa  = (float*)(ws + 201424896);
    float* tot  = (float*)(ws + 203523072);
    uint*  wpk  = (uint*)(ws + 203785216);

    const bool packedW = (ws_size >= 209290240ULL);
    uint* wpk_weight = wpk;                 //   65,536
    uint* wpk_wqkv   = wpk + 65536;         //  589,824
    uint* wpk_wo     = wpk + 655360;        //  196,608
    uint* wpk_fc1    = wpk + 851968;        //  262,144
    uint* wpk_fc2    = wpk + 1114112;       //  262,144  -> end 1,376,256 u32

    if (packedW) {
        pack_k<<<256,  256, 0, stream>>>(weight, wpk_weight, 65536);
        pack_k<<<2304, 256, 0, stream>>>(Wqkv,   wpk_wqkv,   589824);
        pack_k<<<768,  256, 0, stream>>>(Wo,     wpk_wo,     196608);
        pack_k<<<1024, 256, 0, stream>>>(fc1_w,  wpk_fc1,    262144);
        pack_k<<<1024, 256, 0, stream>>>(fc2_w,  wpk_fc2,    262144);
    }

    // helper: launch mm_k with packed or fp32 W
    #define MM(ASRCV, grid, Ap_, Wf_, Wp_, Op_, bias_, rsa_, M_, K_, NC_, fl_)                   \
        do { if (packedW) mm_k<ASRCV,0><<<grid,256,0,stream>>>((Ap_),(const void*)(Wp_),(Op_),    \
                                                 (bias_),(rsa_),(M_),(K_),(NC_),(fl_));          \
             else         mm_k<ASRCV,1><<<grid,256,0,stream>>>((Ap_),(const void*)(Wf_),(Op_),    \
                                                 (bias_),(rsa_),(M_),(K_),(NC_),(fl_)); } while(0)

    // pack x into zpk (consumed by embed GEMM, then ln_k overwrites zpk)
    pack_k<<<65536, 256, 0, stream>>>(x, zpk, AA * BB * CC);
    row0_k<<<AA, 256, 0, stream>>>(out, cls, bias);
    // embed: out[i,1+j,:] = x[i,j,:] @ weight^T + bias
    MM(0, dim3(512, 2), zpk, weight, wpk_weight, out, bias, nullptr,
       AA * BB, CC, CC, F_ROWMAP | F_BIAS2D);

    const int MT = (NROWS + 127) / 128;   // 513
    for (int a = 0; a < NBLK; ++a) {
        // Wqkv is (TK=3, 3, HA, DH, C): per-a stride 196608, x-stride 65536
        const float* wqf = Wqkv + (size_t)a * 196608;
        uint*        wqp = wpk_wqkv + (size_t)a * 196608;
        ln_k<<<NROWS / 4, 256, 0, stream>>>(out, zpk, ln1_g, ln1_b);
        MM(0, dim3(MT, 2), zpk, wqf,          wqp,          qbuf, nullptr, nullptr,
           NROWS, CC, CC, 0);
        MM(0, dim3(MT, 2), zpk, wqf + 65536,  wqp + 65536,  kbuf, nullptr, nullptr,
           NROWS, CC, CC, 0);
        rsa_k<<<NROWS / 4, 256, 0, stream>>>(qbuf, kbuf, rsa);
        // v-gemm with rsa scaling -> imv (overlays qbuf, consumed by rsa_k)
        MM(0, dim3(MT, 2), zpk, wqf + 131072, wqp + 131072, imv, nullptr, rsa,
           NROWS, CC, CC, F_RSAE);
        cumsum1_k<<<256, 256, 0, stream>>>(imv, tot);
        cumsum2_k<<<288, 256, 0, stream>>>((uint*)imv, tot);   // imv now packed-split
        // savespace += imvpk @ Wo[a]^T
        MM(0, dim3(MT, 2), (uint*)imv, Wo + (size_t)a * 65536, wpk_wo + (size_t)a * 65536,
           out, nullptr, nullptr, NROWS, CC, CC, F_RESID);
        ln_k<<<NROWS / 4, 256, 0, stream>>>(out, zpk, ln2_g, ln2_b);
        // h = gelu(z @ fc1_w^T + fc1_b) -> bf16 spanning R1+R2
        MM(0, dim3(MT, 8), zpk, fc1_w, wpk_fc1, hbuf, fc1_b, nullptr,
           NROWS, CC, FFN, F_BIAS1D | F_GELU | F_OUTB16);
        // savespace += h @ fc2_w^T + fc2_b
        MM(1, dim3(MT, 2), hbuf, fc2_w, wpk_fc2, out, fc2_b, nullptr,
           NROWS, FFN, CC, F_BIAS1D | F_RESID);
    }
    #undef MM
}

// Round 8
// 2408.569 us; speedup vs baseline: 2.4876x; 1.2545x over previous
//
#include <hip/hip_runtime.h>
#include <math.h>

#define AA 32
#define BB 2048
#define BP1 2049
#define CC 256
#define NROWS (AA * BP1)          // 65568
#define NBLK 3
#define FFN 1024

typedef unsigned int uint;
typedef unsigned short ushort_t;
typedef __attribute__((ext_vector_type(4))) float f32x4;
typedef __attribute__((ext_vector_type(8))) short short8;

// epilogue flag bits for mm_k (wave-uniform runtime flags)
#define F_RSAE   1
#define F_ROWMAP 2
#define F_BIAS2D 4
#define F_BIAS1D 8
#define F_GELU   16
#define F_RESID  32
#define F_OUTB16 64

__device__ __forceinline__ float bf2f(ushort_t u) {
    return __uint_as_float(((uint)u) << 16);
}
__device__ __forceinline__ ushort_t f2b(float x) {   // fp32 -> bf16 RNE
    uint u = __float_as_uint(x);
    u += 0x7fff + ((u >> 16) & 1);
    return (ushort_t)(u >> 16);
}

// global -> LDS direct 16B load (CK's amd_direct_load pattern)
typedef const uint __attribute__((address_space(1)))* gas_t;
typedef uint __attribute__((address_space(3)))* las_t;
__device__ __forceinline__ void gload16(const ushort_t* g, const short* l) {
    __builtin_amdgcn_global_load_lds(
        reinterpret_cast<gas_t>(reinterpret_cast<uintptr_t>(g)),
        reinterpret_cast<las_t>(static_cast<uint>(reinterpret_cast<uintptr_t>(l))),
        16, 0, 0);
}

// ---------------- fp32 -> two bf16 planes (hi, lo) ----------------
__global__ __launch_bounds__(256) void pack2_k(const float* __restrict__ src,
                                               ushort_t* __restrict__ dh,
                                               ushort_t* __restrict__ dl, int n) {
    int i = blockIdx.x * 256 + threadIdx.x;
    if (i < n) {
        float v = src[i];
        ushort_t h = f2b(v);
        dh[i] = h;
        dl[i] = f2b(v - bf2f(h));
    }
}

// ---------------- row 0 of each batch: cls + bias ----------------
__global__ __launch_bounds__(256) void row0_k(float* __restrict__ out,
                                              const float* __restrict__ cls,
                                              const float* __restrict__ bias) {
    int i = blockIdx.x, t = threadIdx.x;
    size_t o = (size_t)i * BP1 * CC + t;
    out[o] = cls[i * CC + t] + bias[o];
}

// ---------------- layernorm f32 -> split planes ----------------
__global__ __launch_bounds__(256) void ln_k(const float* __restrict__ in,
                                            ushort_t* __restrict__ zh, ushort_t* __restrict__ zl,
                                            const float* __restrict__ g, const float* __restrict__ b) {
    int row = blockIdx.x * 4 + (threadIdx.x >> 6);
    int lane = threadIdx.x & 63;
    const float4 v = *reinterpret_cast<const float4*>(in + (size_t)row * CC + lane * 4);
    float s = v.x + v.y + v.z + v.w;
    float sq = v.x * v.x + v.y * v.y + v.z * v.z + v.w * v.w;
    #pragma unroll
    for (int m = 1; m < 64; m <<= 1) { s += __shfl_xor(s, m); sq += __shfl_xor(sq, m); }
    float mu = s * (1.0f / CC);
    float var = sq * (1.0f / CC) - mu * mu;
    float rs = rsqrtf(var + 1e-5f);
    const float4 gg = *reinterpret_cast<const float4*>(g + lane * 4);
    const float4 bb = *reinterpret_cast<const float4*>(b + lane * 4);
    float o[4];
    o[0] = (v.x - mu) * rs * gg.x + bb.x;
    o[1] = (v.y - mu) * rs * gg.y + bb.y;
    o[2] = (v.z - mu) * rs * gg.z + bb.z;
    o[3] = (v.w - mu) * rs * gg.w + bb.w;
    ushort4 hs, ls;
    hs.x = f2b(o[0]); ls.x = f2b(o[0] - bf2f(hs.x));
    hs.y = f2b(o[1]); ls.y = f2b(o[1] - bf2f(hs.y));
    hs.z = f2b(o[2]); ls.z = f2b(o[2] - bf2f(hs.z));
    hs.w = f2b(o[3]); ls.w = f2b(o[3] - bf2f(hs.w));
    size_t base = (size_t)row * CC + lane * 4;
    *reinterpret_cast<ushort4*>(zh + base) = hs;
    *reinterpret_cast<ushort4*>(zl + base) = ls;
}

// ---------------- rsa[r][h] = (q.k)/sqrt(32) ----------------
__global__ __launch_bounds__(256) void rsa_k(const float* __restrict__ qb,
                                             const float* __restrict__ kb,
                                             float* __restrict__ rsa) {
    int row = blockIdx.x * 4 + (threadIdx.x >> 6);
    int l = threadIdx.x & 63;
    const float4 q4 = *reinterpret_cast<const float4*>(qb + (size_t)row * CC + l * 4);
    const float4 k4 = *reinterpret_cast<const float4*>(kb + (size_t)row * CC + l * 4);
    float p = q4.x * k4.x + q4.y * k4.y + q4.z * k4.z + q4.w * k4.w;
    p += __shfl_xor(p, 1); p += __shfl_xor(p, 2); p += __shfl_xor(p, 4);
    if ((l & 7) == 0) rsa[(size_t)row * 8 + (l >> 3)] = p * 0.17677669529663689f;
}

// ---------------- cumsum pass 1: per-chunk totals (read-only, 8 x 256 rows) ----------------
__global__ __launch_bounds__(256) void cumsum1_k(const float* __restrict__ imv, float* __restrict__ tot) {
    int bi = blockIdx.x >> 3, ch = blockIdx.x & 7, c = threadIdx.x;
    size_t base = ((size_t)bi * BP1 + ch * 256) * CC + c;
    float s = 0.f;
    for (int j = 0; j < 256; ++j) s += imv[base + (size_t)j * CC];
    tot[((size_t)bi * 8 + ch) * CC + c] = s;
}

// ---------------- cumsum pass 2: scan + offset -> split planes ----------------
__global__ __launch_bounds__(256) void cumsum2_k(const float* __restrict__ imv,
                                                 const float* __restrict__ tot,
                                                 ushort_t* __restrict__ ph,
                                                 ushort_t* __restrict__ pl) {
    int bi = blockIdx.x / 9, ch = blockIdx.x - bi * 9, c = threadIdx.x;
    if (ch == 8) {   // row BB (untouched by cumsum): just split-pack
        size_t idx = ((size_t)bi * BP1 + BB) * CC + c;
        float v = imv[idx];
        ushort_t h = f2b(v);
        ph[idx] = h; pl[idx] = f2b(v - bf2f(h));
        return;
    }
    float s = 0.f;
    for (int q = 0; q < ch; ++q) s += tot[((size_t)bi * 8 + q) * CC + c];
    size_t base = ((size_t)bi * BP1 + ch * 256) * CC + c;
    for (int j = 0; j < 256; ++j) {
        s += imv[base + (size_t)j * CC];
        ushort_t h = f2b(s);
        ph[base + (size_t)j * CC] = h;
        pl[base + (size_t)j * CC] = f2b(s - bf2f(h));
    }
}

// ---------------- split-bf16 MFMA GEMM, plane operands + global_load_lds ----------------
// Out(MxN) = A(MxK) * W(NxK)^T ; A planes (Ah,Al[ALO]), W planes (Bh,Bl) all bf16 row-major.
// grid: blockIdx.x = n-tile, blockIdx.y = m-tile (A-panel shared by consecutive blocks)
template<int ALO>
__global__ __launch_bounds__(256) void mm_k(const ushort_t* __restrict__ Ah_g,
                                            const ushort_t* __restrict__ Al_g,
                                            const ushort_t* __restrict__ Bh_g,
                                            const ushort_t* __restrict__ Bl_g,
                                            void* __restrict__ Op,
                                            const float* __restrict__ bias,
                                            const float* __restrict__ rsa,
                                            int M, int K, int NC, int flags) {
    // linear planes: 128 rows x 32 k bf16 (8 KB each)
    __shared__ __align__(16) short As_h[4096];
    __shared__ __align__(16) short As_l[4096];
    __shared__ __align__(16) short Bs_h[4096];
    __shared__ __align__(16) short Bs_l[4096];
    const int t = threadIdx.x;
    const int n0 = blockIdx.x * 128, m0 = blockIdx.y * 128;
    const int wid = t >> 6, l = t & 63;
    const int wr = wid >> 1, wc = wid & 1;

    // staging geometry: wave w covers 1KB chunks (w) and (w+4); lane l -> row l>>2, col (l&3)*8
    const int ch0 = wid, ch1 = wid + 4;
    const int sr0 = ch0 * 16 + (l >> 2);
    const int sr1 = ch1 * 16 + (l >> 2);
    const int sc  = (l & 3) * 8;
    int ga0 = m0 + sr0; if (ga0 >= M) ga0 = M - 1;
    int ga1 = m0 + sr1; if (ga1 >= M) ga1 = M - 1;
    const int gb0 = n0 + sr0, gb1 = n0 + sr1;

    f32x4 acc[4][4];
    #pragma unroll
    for (int i = 0; i < 4; ++i)
        #pragma unroll
        for (int j = 0; j < 4; ++j) acc[i][j] = (f32x4)(0.0f);

    for (int k0 = 0; k0 < K; k0 += 32) {
        // ---- stage via global_load_lds (wave-uniform LDS base + lane*16) ----
        gload16(Ah_g + (size_t)ga0 * K + k0 + sc, &As_h[ch0 * 512]);
        gload16(Ah_g + (size_t)ga1 * K + k0 + sc, &As_h[ch1 * 512]);
        if (ALO) {
            gload16(Al_g + (size_t)ga0 * K + k0 + sc, &As_l[ch0 * 512]);
            gload16(Al_g + (size_t)ga1 * K + k0 + sc, &As_l[ch1 * 512]);
        }
        gload16(Bh_g + (size_t)gb0 * K + k0 + sc, &Bs_h[ch0 * 512]);
        gload16(Bh_g + (size_t)gb1 * K + k0 + sc, &Bs_h[ch1 * 512]);
        gload16(Bl_g + (size_t)gb0 * K + k0 + sc, &Bs_l[ch0 * 512]);
        gload16(Bl_g + (size_t)gb1 * K + k0 + sc, &Bs_l[ch1 * 512]);
        __syncthreads();                       // compiler drains vmcnt before barrier
        // ---- fragments + MFMA ----
        short8 ah[4], al[4], bh[4], bl[4];
        #pragma unroll
        for (int i = 0; i < 4; ++i) {
            int ro = (wr * 64 + i * 16 + (l & 15)) * 32 + (l >> 4) * 8;
            ah[i] = *reinterpret_cast<const short8*>(&As_h[ro]);
            if (ALO) al[i] = *reinterpret_cast<const short8*>(&As_l[ro]);
        }
        #pragma unroll
        for (int j = 0; j < 4; ++j) {
            int ro = (wc * 64 + j * 16 + (l & 15)) * 32 + (l >> 4) * 8;
            bh[j] = *reinterpret_cast<const short8*>(&Bs_h[ro]);
            bl[j] = *reinterpret_cast<const short8*>(&Bs_l[ro]);
        }
        #pragma unroll
        for (int i = 0; i < 4; ++i)
            #pragma unroll
            for (int j = 0; j < 4; ++j) {
                acc[i][j] = __builtin_amdgcn_mfma_f32_16x16x32_bf16(ah[i], bh[j], acc[i][j], 0, 0, 0);
                acc[i][j] = __builtin_amdgcn_mfma_f32_16x16x32_bf16(ah[i], bl[j], acc[i][j], 0, 0, 0);
                if (ALO)
                    acc[i][j] = __builtin_amdgcn_mfma_f32_16x16x32_bf16(al[i], bh[j], acc[i][j], 0, 0, 0);
            }
        __syncthreads();                       // LDS reuse guard
    }

    // ---- epilogue (runtime flags, wave-uniform) ----
    #pragma unroll
    for (int i = 0; i < 4; ++i)
        #pragma unroll
        for (int j = 0; j < 4; ++j) {
            int colb = n0 + wc * 64 + j * 16 + (l & 15);
            #pragma unroll
            for (int r = 0; r < 4; ++r) {
                int row = m0 + wr * 64 + i * 16 + (l >> 4) * 4 + r;
                if (row >= M) continue;
                float v = acc[i][j][r];
                size_t g = (flags & F_ROWMAP) ? ((size_t)(row >> 11) * BP1 + 1 + (row & 2047))
                                             : (size_t)row;
                if (flags & F_RSAE)   v *= rsa[g * 8 + (colb >> 5)];
                if (flags & F_BIAS1D) v += bias[colb];
                if (flags & F_BIAS2D) v += bias[g * (size_t)NC + colb];
                if (flags & F_GELU)   v = 0.5f * v * (1.0f + erff(v * 0.70710678118654752f));
                size_t oi = g * (size_t)NC + colb;
                if (flags & F_OUTB16) {
                    reinterpret_cast<ushort_t*>(Op)[oi] = f2b(v);
                } else {
                    float* O = reinterpret_cast<float*>(Op);
                    if (flags & F_RESID) v += O[oi];
                    O[oi] = v;
                }
            }
        }
}

// ---------------- launch ----------------
extern "C" void kernel_launch(void* const* d_in, const int* in_sizes, int n_in,
                              void* d_out, int out_size, void* d_ws, size_t ws_size,
                              hipStream_t stream) {
    const float* x      = (const float*)d_in[0];
    const float* weight = (const float*)d_in[1];
    const float* bias   = (const float*)d_in[2];
    const float* cls    = (const float*)d_in[3];
    const float* Wqkv   = (const float*)d_in[4];
    const float* Wo     = (const float*)d_in[5];
    const float* ln1_g  = (const float*)d_in[6];
    const float* ln1_b  = (const float*)d_in[7];
    const float* ln2_g  = (const float*)d_in[8];
    const float* ln2_b  = (const float*)d_in[9];
    const float* fc1_w  = (const float*)d_in[10];
    const float* fc1_b  = (const float*)d_in[11];
    const float* fc2_w  = (const float*)d_in[12];
    const float* fc2_b  = (const float*)d_in[13];
    float* out = (float*)d_out;

    // ---- workspace (high-water 209,290,240 B — proven in round 7) ----
    // zh  [0,          33,570,816)  NROWS*256 bf16 hi plane (x, then z)
    // zl  [33,570,816, 67,141,632)  lo plane
    // R1  [67,141,632,134,283,264)  qbuf f32 -> imv f32 -> hbuf lower half
    // R2  [134,283,264,201,424,896) kbuf f32 -> imh+iml planes -> hbuf upper half
    // rsa [201,424,896,203,523,072)
    // tot [203,523,072,203,785,216)
    // wp  [203,785,216,209,290,240) weight planes (hi|lo per weight)
    char* ws = (char*)d_ws;
    ushort_t* zh   = (ushort_t*)(ws + 0);
    ushort_t* zl   = (ushort_t*)(ws + 33570816);
    float*    qbuf = (float*)(ws + 67141632);
    float*    imv  = (float*)(ws + 67141632);                  // overlays qbuf
    float*    kbuf = (float*)(ws + 134283264);
    ushort_t* imh  = (ushort_t*)(ws + 134283264);              // overlays kbuf
    ushort_t* iml  = (ushort_t*)(ws + 167854080);
    ushort_t* hbuf = (ushort_t*)(ws + 67141632);               // spans R1+R2
    float*    rsa  = (float*)(ws + 201424896);
    float*    tot  = (float*)(ws + 203523072);
    ushort_t* wp   = (ushort_t*)(ws + 203785216);

    ushort_t* w_h    = wp;                 // weight  65,536
    ushort_t* w_l    = wp + 65536;
    ushort_t* wqkv_h = wp + 131072;        // Wqkv   589,824
    ushort_t* wqkv_l = wp + 720896;
    ushort_t* wo_h   = wp + 1310720;       // Wo     196,608
    ushort_t* wo_l   = wp + 1507328;
    ushort_t* fc1_h  = wp + 1703936;       // fc1    262,144
    ushort_t* fc1_l  = wp + 1966080;
    ushort_t* fc2_h  = wp + 2228224;       // fc2    262,144
    ushort_t* fc2_l  = wp + 2490368;       // end 2,752,512 us -> 209,290,240 B

    // weight plane packs (cheap, every call)
    pack2_k<<<256,  256, 0, stream>>>(weight, w_h,    w_l,    65536);
    pack2_k<<<2304, 256, 0, stream>>>(Wqkv,   wqkv_h, wqkv_l, 589824);
    pack2_k<<<768,  256, 0, stream>>>(Wo,     wo_h,   wo_l,   196608);
    pack2_k<<<1024, 256, 0, stream>>>(fc1_w,  fc1_h,  fc1_l,  262144);
    pack2_k<<<1024, 256, 0, stream>>>(fc2_w,  fc2_h,  fc2_l,  262144);
    // pack x into z planes (consumed by embed GEMM, then ln_k overwrites)
    pack2_k<<<65536, 256, 0, stream>>>(x, zh, zl, AA * BB * CC);

    row0_k<<<AA, 256, 0, stream>>>(out, cls, bias);
    // embed: out[i,1+j,:] = x[i,j,:] @ weight^T + bias
    mm_k<1><<<dim3(2, 512), 256, 0, stream>>>(zh, zl, w_h, w_l, out, bias, nullptr,
                                              AA * BB, CC, CC, F_ROWMAP | F_BIAS2D);

    const int MT = (NROWS + 127) / 128;   // 513
    for (int a = 0; a < NBLK; ++a) {
        // Wqkv (TK,3,HA,DH,C): per-a stride 196608, x-stride 65536
        const size_t aw = (size_t)a * 196608;
        ln_k<<<NROWS / 4, 256, 0, stream>>>(out, zh, zl, ln1_g, ln1_b);
        mm_k<1><<<dim3(2, MT), 256, 0, stream>>>(zh, zl, wqkv_h + aw,          wqkv_l + aw,
                                                 qbuf, nullptr, nullptr, NROWS, CC, CC, 0);
        mm_k<1><<<dim3(2, MT), 256, 0, stream>>>(zh, zl, wqkv_h + aw + 65536,  wqkv_l + aw + 65536,
                                                 kbuf, nullptr, nullptr, NROWS, CC, CC, 0);
        rsa_k<<<NROWS / 4, 256, 0, stream>>>(qbuf, kbuf, rsa);
        // v-gemm with rsa scaling -> imv (overlays qbuf, consumed by rsa_k)
        mm_k<1><<<dim3(2, MT), 256, 0, stream>>>(zh, zl, wqkv_h + aw + 131072, wqkv_l + aw + 131072,
                                                 imv, nullptr, rsa, NROWS, CC, CC, F_RSAE);
        cumsum1_k<<<256, 256, 0, stream>>>(imv, tot);
        cumsum2_k<<<288, 256, 0, stream>>>(imv, tot, imh, iml);   // kbuf dead
        // savespace += im @ Wo[a]^T
        mm_k<1><<<dim3(2, MT), 256, 0, stream>>>(imh, iml, wo_h + (size_t)a * 65536,
                                                 wo_l + (size_t)a * 65536, out, nullptr, nullptr,
                                                 NROWS, CC, CC, F_RESID);
        ln_k<<<NROWS / 4, 256, 0, stream>>>(out, zh, zl, ln2_g, ln2_b);
        // h = gelu(z @ fc1^T + b) -> bf16 hbuf spanning R1+R2 (imv, imh/iml dead)
        mm_k<1><<<dim3(8, MT), 256, 0, stream>>>(zh, zl, fc1_h, fc1_l, hbuf, fc1_b, nullptr,
                                                 NROWS, CC, FFN, F_BIAS1D | F_GELU | F_OUTB16);
        // savespace += h @ fc2^T + b  (A single plane)
        mm_k<0><<<dim3(2, MT), 256, 0, stream>>>(hbuf, nullptr, fc2_h, fc2_l, out, fc2_b, nullptr,
                                                 NROWS, FFN, CC, F_BIAS1D | F_RESID);
    }
}

// Round 9
// 2200.970 us; speedup vs baseline: 2.7222x; 1.0943x over previous
//
#include <hip/hip_runtime.h>
#include <math.h>

#define AA 32
#define BB 2048
#define BP1 2049
#define CC 256
#define NROWS (AA * BP1)          // 65568
#define NBLK 3
#define FFN 1024

typedef unsigned int uint;
typedef unsigned short ushort_t;
typedef __attribute__((ext_vector_type(4))) float f32x4;
typedef __attribute__((ext_vector_type(8))) short short8;

// epilogue flag bits for mm_k (wave-uniform runtime flags)
#define F_ROWMAP 2
#define F_BIAS2D 4
#define F_BIAS1D 8
#define F_GELU   16
#define F_RESID  32
#define F_OUTB16 64
#define F_QKV    128

__device__ __forceinline__ float bf2f(ushort_t u) {
    return __uint_as_float(((uint)u) << 16);
}
__device__ __forceinline__ ushort_t f2b(float x) {   // fp32 -> bf16 RNE
    uint u = __float_as_uint(x);
    u += 0x7fff + ((u >> 16) & 1);
    return (ushort_t)(u >> 16);
}

// global -> LDS direct 16B load
typedef const uint __attribute__((address_space(1)))* gas_t;
typedef uint __attribute__((address_space(3)))* las_t;
__device__ __forceinline__ void gload16(const ushort_t* g, const short* l) {
    __builtin_amdgcn_global_load_lds(
        reinterpret_cast<gas_t>(reinterpret_cast<uintptr_t>(g)),
        reinterpret_cast<las_t>(static_cast<uint>(reinterpret_cast<uintptr_t>(l))),
        16, 0, 0);
}

// ---------------- fp32 -> two bf16 planes (hi, lo) ----------------
__global__ __launch_bounds__(256) void pack2_k(const float* __restrict__ src,
                                               ushort_t* __restrict__ dh,
                                               ushort_t* __restrict__ dl, int n) {
    int i = blockIdx.x * 256 + threadIdx.x;
    if (i < n) {
        float v = src[i];
        ushort_t h = f2b(v);
        dh[i] = h;
        dl[i] = f2b(v - bf2f(h));
    }
}

// ---------------- row 0 of each batch: cls + bias ----------------
__global__ __launch_bounds__(256) void row0_k(float* __restrict__ out,
                                              const float* __restrict__ cls,
                                              const float* __restrict__ bias) {
    int i = blockIdx.x, t = threadIdx.x;
    size_t o = (size_t)i * BP1 * CC + t;
    out[o] = cls[i * CC + t] + bias[o];
}

// ---------------- layernorm f32 -> split planes ----------------
__global__ __launch_bounds__(256) void ln_k(const float* __restrict__ in,
                                            ushort_t* __restrict__ zh, ushort_t* __restrict__ zl,
                                            const float* __restrict__ g, const float* __restrict__ b) {
    int row = blockIdx.x * 4 + (threadIdx.x >> 6);
    int lane = threadIdx.x & 63;
    const float4 v = *reinterpret_cast<const float4*>(in + (size_t)row * CC + lane * 4);
    float s = v.x + v.y + v.z + v.w;
    float sq = v.x * v.x + v.y * v.y + v.z * v.z + v.w * v.w;
    #pragma unroll
    for (int m = 1; m < 64; m <<= 1) { s += __shfl_xor(s, m); sq += __shfl_xor(sq, m); }
    float mu = s * (1.0f / CC);
    float var = sq * (1.0f / CC) - mu * mu;
    float rs = rsqrtf(var + 1e-5f);
    const float4 gg = *reinterpret_cast<const float4*>(g + lane * 4);
    const float4 bb = *reinterpret_cast<const float4*>(b + lane * 4);
    float o[4];
    o[0] = (v.x - mu) * rs * gg.x + bb.x;
    o[1] = (v.y - mu) * rs * gg.y + bb.y;
    o[2] = (v.z - mu) * rs * gg.z + bb.z;
    o[3] = (v.w - mu) * rs * gg.w + bb.w;
    ushort4 hs, ls;
    hs.x = f2b(o[0]); ls.x = f2b(o[0] - bf2f(hs.x));
    hs.y = f2b(o[1]); ls.y = f2b(o[1] - bf2f(hs.y));
    hs.z = f2b(o[2]); ls.z = f2b(o[2] - bf2f(hs.z));
    hs.w = f2b(o[3]); ls.w = f2b(o[3] - bf2f(hs.w));
    size_t base = (size_t)row * CC + lane * 4;
    *reinterpret_cast<ushort4*>(zh + base) = hs;
    *reinterpret_cast<ushort4*>(zl + base) = ls;
}

// ---------------- rsa from bf16 qk buffer: rsa[r][h] = (q.k)/sqrt(32) ----------------
__global__ __launch_bounds__(256) void rsa2_k(const ushort_t* __restrict__ qk,
                                              float* __restrict__ rsa) {
    int row = blockIdx.x * 4 + (threadIdx.x >> 6);
    int l = threadIdx.x & 63;
    const ushort4 qa = *reinterpret_cast<const ushort4*>(qk + (size_t)row * 512 + l * 4);
    const ushort4 ka = *reinterpret_cast<const ushort4*>(qk + (size_t)row * 512 + 256 + l * 4);
    float p = bf2f(qa.x) * bf2f(ka.x) + bf2f(qa.y) * bf2f(ka.y)
            + bf2f(qa.z) * bf2f(ka.z) + bf2f(qa.w) * bf2f(ka.w);
    p += __shfl_xor(p, 1); p += __shfl_xor(p, 2); p += __shfl_xor(p, 4);
    if ((l & 7) == 0) rsa[(size_t)row * 8 + (l >> 3)] = p * 0.17677669529663689f;
}

// ---------------- cumsum pass 1: per-chunk totals of rsa*v (read-only) ----------------
__global__ __launch_bounds__(256) void cumsum1_k(const float* __restrict__ v,
                                                 const float* __restrict__ rsa,
                                                 float* __restrict__ tot) {
    int bi = blockIdx.x >> 3, ch = blockIdx.x & 7, c = threadIdx.x;
    int h = c >> 5;
    size_t row0 = (size_t)bi * BP1 + ch * 256;
    float s = 0.f;
    for (int j = 0; j < 256; ++j)
        s += v[(row0 + j) * CC + c] * rsa[(row0 + j) * 8 + h];
    tot[((size_t)bi * 8 + ch) * CC + c] = s;
}

// ---------------- cumsum pass 2: scan rsa*v + offset -> split planes ----------------
__global__ __launch_bounds__(256) void cumsum2_k(const float* __restrict__ v,
                                                 const float* __restrict__ rsa,
                                                 const float* __restrict__ tot,
                                                 ushort_t* __restrict__ ph,
                                                 ushort_t* __restrict__ pl) {
    int bi = blockIdx.x / 9, ch = blockIdx.x - bi * 9, c = threadIdx.x;
    int h = c >> 5;
    if (ch == 8) {   // row BB (untouched by cumsum): scale + split-pack
        size_t row = (size_t)bi * BP1 + BB;
        float val = v[row * CC + c] * rsa[row * 8 + h];
        ushort_t hh = f2b(val);
        ph[row * CC + c] = hh; pl[row * CC + c] = f2b(val - bf2f(hh));
        return;
    }
    float s = 0.f;
    for (int q = 0; q < ch; ++q) s += tot[((size_t)bi * 8 + q) * CC + c];
    size_t row0 = (size_t)bi * BP1 + ch * 256;
    for (int j = 0; j < 256; ++j) {
        size_t row = row0 + j;
        s += v[row * CC + c] * rsa[row * 8 + h];
        ushort_t hh = f2b(s);
        ph[row * CC + c] = hh;
        pl[row * CC + c] = f2b(s - bf2f(hh));
    }
}

// ---------------- split-bf16 MFMA GEMM, plane operands + global_load_lds ----------------
// Out(MxN) = A(MxK) * W(NxK)^T ; 1-D grid = NT*MT, XCD-bijective swizzle, n-fastest raster.
// F_QKV: cols<512 -> bf16 Op (stride 512), cols>=512 -> fp32 Op2 (stride 256, col-512)
template<int ALO>
__global__ __launch_bounds__(256) void mm_k(const ushort_t* __restrict__ Ah_g,
                                            const ushort_t* __restrict__ Al_g,
                                            const ushort_t* __restrict__ Bh_g,
                                            const ushort_t* __restrict__ Bl_g,
                                            void* __restrict__ Op,
                                            void* __restrict__ Op2,
                                            const float* __restrict__ bias,
                                            int M, int K, int NC, int NT, int flags) {
    __shared__ __align__(16) short As_h[4096];
    __shared__ __align__(16) short As_l[4096];
    __shared__ __align__(16) short Bs_h[4096];
    __shared__ __align__(16) short Bs_l[4096];
    const int t = threadIdx.x;

    // XCD-bijective block swizzle (m204): each XCD gets a contiguous wgid chunk
    const int nwg = gridDim.x;
    const int q8 = nwg >> 3, r8 = nwg & 7;
    const int xcd = blockIdx.x & 7, ii = blockIdx.x >> 3;
    const int wgid = (xcd < r8 ? xcd * (q8 + 1) : r8 * (q8 + 1) + (xcd - r8) * q8) + ii;
    const int nt = wgid % NT, mt = wgid / NT;
    const int n0 = nt * 128, m0 = mt * 128;

    const int wid = t >> 6, l = t & 63;
    const int wr = wid >> 1, wc = wid & 1;

    // staging geometry: wave w covers 1KB chunks (w) and (w+4); lane l -> row l>>2, col (l&3)*8
    const int ch0 = wid, ch1 = wid + 4;
    const int sr0 = ch0 * 16 + (l >> 2);
    const int sr1 = ch1 * 16 + (l >> 2);
    const int sc  = (l & 3) * 8;
    int ga0 = m0 + sr0; if (ga0 >= M) ga0 = M - 1;
    int ga1 = m0 + sr1; if (ga1 >= M) ga1 = M - 1;
    const int gb0 = n0 + sr0, gb1 = n0 + sr1;

    f32x4 acc[4][4];
    #pragma unroll
    for (int i = 0; i < 4; ++i)
        #pragma unroll
        for (int j = 0; j < 4; ++j) acc[i][j] = (f32x4)(0.0f);

    for (int k0 = 0; k0 < K; k0 += 32) {
        gload16(Ah_g + (size_t)ga0 * K + k0 + sc, &As_h[ch0 * 512]);
        gload16(Ah_g + (size_t)ga1 * K + k0 + sc, &As_h[ch1 * 512]);
        if (ALO) {
            gload16(Al_g + (size_t)ga0 * K + k0 + sc, &As_l[ch0 * 512]);
            gload16(Al_g + (size_t)ga1 * K + k0 + sc, &As_l[ch1 * 512]);
        }
        gload16(Bh_g + (size_t)gb0 * K + k0 + sc, &Bs_h[ch0 * 512]);
        gload16(Bh_g + (size_t)gb1 * K + k0 + sc, &Bs_h[ch1 * 512]);
        gload16(Bl_g + (size_t)gb0 * K + k0 + sc, &Bs_l[ch0 * 512]);
        gload16(Bl_g + (size_t)gb1 * K + k0 + sc, &Bs_l[ch1 * 512]);
        __syncthreads();
        short8 ah[4], al[4], bh[4], bl[4];
        #pragma unroll
        for (int i = 0; i < 4; ++i) {
            int ro = (wr * 64 + i * 16 + (l & 15)) * 32 + (l >> 4) * 8;
            ah[i] = *reinterpret_cast<const short8*>(&As_h[ro]);
            if (ALO) al[i] = *reinterpret_cast<const short8*>(&As_l[ro]);
        }
        #pragma unroll
        for (int j = 0; j < 4; ++j) {
            int ro = (wc * 64 + j * 16 + (l & 15)) * 32 + (l >> 4) * 8;
            bh[j] = *reinterpret_cast<const short8*>(&Bs_h[ro]);
            bl[j] = *reinterpret_cast<const short8*>(&Bs_l[ro]);
        }
        #pragma unroll
        for (int i = 0; i < 4; ++i)
            #pragma unroll
            for (int j = 0; j < 4; ++j) {
                acc[i][j] = __builtin_amdgcn_mfma_f32_16x16x32_bf16(ah[i], bh[j], acc[i][j], 0, 0, 0);
                acc[i][j] = __builtin_amdgcn_mfma_f32_16x16x32_bf16(ah[i], bl[j], acc[i][j], 0, 0, 0);
                if (ALO)
                    acc[i][j] = __builtin_amdgcn_mfma_f32_16x16x32_bf16(al[i], bh[j], acc[i][j], 0, 0, 0);
            }
        __syncthreads();
    }

    // ---- epilogue ----
    #pragma unroll
    for (int i = 0; i < 4; ++i)
        #pragma unroll
        for (int j = 0; j < 4; ++j) {
            int colb = n0 + wc * 64 + j * 16 + (l & 15);
            #pragma unroll
            for (int r = 0; r < 4; ++r) {
                int row = m0 + wr * 64 + i * 16 + (l >> 4) * 4 + r;
                if (row >= M) continue;
                float v = acc[i][j][r];
                if (flags & F_QKV) {          // block-uniform by n-tile
                    if (colb < 512)
                        reinterpret_cast<ushort_t*>(Op)[(size_t)row * 512 + colb] = f2b(v);
                    else
                        reinterpret_cast<float*>(Op2)[(size_t)row * 256 + (colb - 512)] = v;
                    continue;
                }
                size_t g = (flags & F_ROWMAP) ? ((size_t)(row >> 11) * BP1 + 1 + (row & 2047))
                                             : (size_t)row;
                if (flags & F_BIAS1D) v += bias[colb];
                if (flags & F_BIAS2D) v += bias[g * (size_t)NC + colb];
                if (flags & F_GELU)   v = 0.5f * v * (1.0f + erff(v * 0.70710678118654752f));
                size_t oi = g * (size_t)NC + colb;
                if (flags & F_OUTB16) {
                    reinterpret_cast<ushort_t*>(Op)[oi] = f2b(v);
                } else {
                    float* O = reinterpret_cast<float*>(Op);
                    if (flags & F_RESID) v += O[oi];
                    O[oi] = v;
                }
            }
        }
}

// ---------------- launch ----------------
extern "C" void kernel_launch(void* const* d_in, const int* in_sizes, int n_in,
                              void* d_out, int out_size, void* d_ws, size_t ws_size,
                              hipStream_t stream) {
    const float* x      = (const float*)d_in[0];
    const float* weight = (const float*)d_in[1];
    const float* bias   = (const float*)d_in[2];
    const float* cls    = (const float*)d_in[3];
    const float* Wqkv   = (const float*)d_in[4];
    const float* Wo     = (const float*)d_in[5];
    const float* ln1_g  = (const float*)d_in[6];
    const float* ln1_b  = (const float*)d_in[7];
    const float* ln2_g  = (const float*)d_in[8];
    const float* ln2_b  = (const float*)d_in[9];
    const float* fc1_w  = (const float*)d_in[10];
    const float* fc1_b  = (const float*)d_in[11];
    const float* fc2_w  = (const float*)d_in[12];
    const float* fc2_b  = (const float*)d_in[13];
    float* out = (float*)d_out;

    // ---- workspace (high-water 209,290,240 B — proven rounds 7/8) ----
    // zh  [0,          33,570,816)   NROWS*256 bf16 hi plane (x, then z)
    // zl  [33,570,816, 67,141,632)   lo plane
    // R1  [67,141,632,134,283,264)   vbuf f32 -> hbuf lower half
    // R2  [134,283,264,201,424,896)  qkbuf bf16 -> imh+iml planes -> hbuf upper half
    // rsa [201,424,896,203,523,072)
    // tot [203,523,072,203,785,216)
    // wp  [203,785,216,209,290,240)  weight planes (hi|lo per weight)
    char* ws = (char*)d_ws;
    ushort_t* zh    = (ushort_t*)(ws + 0);
    ushort_t* zl    = (ushort_t*)(ws + 33570816);
    float*    vbuf  = (float*)(ws + 67141632);
    ushort_t* qkbuf = (ushort_t*)(ws + 134283264);
    ushort_t* imh   = (ushort_t*)(ws + 134283264);             // overlays qkbuf
    ushort_t* iml   = (ushort_t*)(ws + 167854080);
    ushort_t* hbuf  = (ushort_t*)(ws + 67141632);              // spans R1+R2
    float*    rsa   = (float*)(ws + 201424896);
    float*    tot   = (float*)(ws + 203523072);
    ushort_t* wp    = (ushort_t*)(ws + 203785216);

    ushort_t* w_h    = wp;                 // weight  65,536
    ushort_t* w_l    = wp + 65536;
    ushort_t* wqkv_h = wp + 131072;        // Wqkv   589,824
    ushort_t* wqkv_l = wp + 720896;
    ushort_t* wo_h   = wp + 1310720;       // Wo     196,608
    ushort_t* wo_l   = wp + 1507328;
    ushort_t* fc1_h  = wp + 1703936;       // fc1    262,144
    ushort_t* fc1_l  = wp + 1966080;
    ushort_t* fc2_h  = wp + 2228224;       // fc2    262,144
    ushort_t* fc2_l  = wp + 2490368;       // end 2,752,512 -> 209,290,240 B

    pack2_k<<<256,  256, 0, stream>>>(weight, w_h,    w_l,    65536);
    pack2_k<<<2304, 256, 0, stream>>>(Wqkv,   wqkv_h, wqkv_l, 589824);
    pack2_k<<<768,  256, 0, stream>>>(Wo,     wo_h,   wo_l,   196608);
    pack2_k<<<1024, 256, 0, stream>>>(fc1_w,  fc1_h,  fc1_l,  262144);
    pack2_k<<<1024, 256, 0, stream>>>(fc2_w,  fc2_h,  fc2_l,  262144);
    pack2_k<<<65536, 256, 0, stream>>>(x, zh, zl, AA * BB * CC);

    row0_k<<<AA, 256, 0, stream>>>(out, cls, bias);
    // embed: out[i,1+j,:] = x[i,j,:] @ weight^T + bias  (NT=2, 1024 blocks)
    mm_k<1><<<1024, 256, 0, stream>>>(zh, zl, w_h, w_l, out, nullptr, bias,
                                      AA * BB, CC, CC, 2, F_ROWMAP | F_BIAS2D);

    const int MT = (NROWS + 127) / 128;   // 513
    for (int a = 0; a < NBLK; ++a) {
        const size_t aw = (size_t)a * 196608;   // per-layer Wqkv stride (3*8*32*256)
        ln_k<<<NROWS / 4, 256, 0, stream>>>(out, zh, zl, ln1_g, ln1_b);
        // fused qkv: NC=768 (rows = [Wq;Wk;Wv] stacked), q/k -> bf16 qkbuf, v -> fp32 vbuf
        mm_k<1><<<6 * MT, 256, 0, stream>>>(zh, zl, wqkv_h + aw, wqkv_l + aw,
                                            qkbuf, vbuf, nullptr,
                                            NROWS, CC, 768, 6, F_QKV);
        rsa2_k<<<NROWS / 4, 256, 0, stream>>>(qkbuf, rsa);
        cumsum1_k<<<256, 256, 0, stream>>>(vbuf, rsa, tot);
        cumsum2_k<<<288, 256, 0, stream>>>(vbuf, rsa, tot, imh, iml);  // qkbuf dead
        // savespace += im @ Wo[a]^T
        mm_k<1><<<2 * MT, 256, 0, stream>>>(imh, iml, wo_h + (size_t)a * 65536,
                                            wo_l + (size_t)a * 65536, out, nullptr, nullptr,
                                            NROWS, CC, CC, 2, F_RESID);
        ln_k<<<NROWS / 4, 256, 0, stream>>>(out, zh, zl, ln2_g, ln2_b);
        // h = gelu(z @ fc1^T + b) -> bf16 hbuf spanning R1+R2 (vbuf, im planes dead)
        mm_k<1><<<8 * MT, 256, 0, stream>>>(zh, zl, fc1_h, fc1_l, hbuf, nullptr, fc1_b,
                                            NROWS, CC, FFN, 8, F_BIAS1D | F_GELU | F_OUTB16);
        // savespace += h @ fc2^T + b  (A single plane)
        mm_k<0><<<2 * MT, 256, 0, stream>>>(hbuf, nullptr, fc2_h, fc2_l, out, nullptr, fc2_b,
                                            NROWS, FFN, CC, 2, F_BIAS1D | F_RESID);
    }
}